// Round 1
// baseline (645.543 us; speedup 1.0000x reference)
//
#include <hip/hip_runtime.h>

// DynamicRouting: grouped 1x1 conv (G=8, FI=FO=64) + 3-iter sigmoid routing.
// One 256-thread WG per (b,h) row of 64 pixels.
// Thread = (pixel p = tid&63, fo-quarter q = tid>>6); con[8][16] in VGPRs.
// Weight addresses are wave-uniform (q via readfirstlane) -> scalar loads.

#define NG 8
#define NFO 64
#define NFI 64
#define NB 32
#define NH 64
#define NW 64
#define HW (NH * NW)

__global__ __launch_bounds__(256) void dynrout_kernel(
    const float* __restrict__ x, const float* __restrict__ weight,
    const float* __restrict__ bias, float* __restrict__ out)
{
    const int tid = threadIdx.x;
    const int p = tid & 63;
    const int q = __builtin_amdgcn_readfirstlane(tid >> 6);  // fo-quarter, wave-uniform

    const int wg = blockIdx.x;
    const int b = wg >> 6;
    const int h = wg & 63;

    // x[b][c][h][w]: this thread reads channel c at xrow[c*HW]
    const float* xrow = x + ((size_t)b * (NG * NFI) * HW) + (size_t)h * NW + p;

    float con[8][16];
#pragma unroll
    for (int g = 0; g < 8; ++g)
#pragma unroll
        for (int f = 0; f < 16; ++f) con[g][f] = 0.f;

    // ---- grouped 1x1 conv: con[g][f] = sum_i w[g][q*16+f][i] * x[g*64+i] ----
#pragma unroll
    for (int g = 0; g < 8; ++g) {
        const float* xg = xrow + (size_t)g * NFI * HW;
        const float* wgb = weight + ((size_t)g * NFO + q * 16) * NFI;
#pragma unroll
        for (int ib = 0; ib < 4; ++ib) {
            float xv[16];
#pragma unroll
            for (int j = 0; j < 16; ++j)
                xv[j] = xg[(size_t)(ib * 16 + j) * HW];
#pragma unroll
            for (int f = 0; f < 16; ++f) {
                const float* wr = wgb + f * NFI + ib * 16;
#pragma unroll
                for (int j = 0; j < 16; ++j)
                    con[g][f] = fmaf(wr[j], xv[j], con[g][f]);
            }
        }
    }

    // ---- routing ----
    __shared__ float pbuf[4][8][64];   // per-wave partial beta sums
    __shared__ float alphaS[8][64];
    __shared__ float betaS[8][64];

    float v[16];

    // iter 0: alpha = sigmoid(0) = 0.5; v0 = 0.5 * sum_g con
#pragma unroll
    for (int f = 0; f < 16; ++f) {
        float s = con[0][f];
#pragma unroll
        for (int g = 1; g < 8; ++g) s += con[g][f];
        v[f] = 0.5f * s;
    }
    // beta1[g] = sum_fo v0*con : partial over this wave's 16 fo
#pragma unroll
    for (int g = 0; g < 8; ++g) {
        float s = 0.f;
#pragma unroll
        for (int f = 0; f < 16; ++f) s = fmaf(v[f], con[g][f], s);
        pbuf[q][g][p] = s;
    }
    __syncthreads();
    // reduce 4 partials, sigmoid -> alpha1; keep beta1
    for (int k = tid; k < 512; k += 256) {
        const int gg = k >> 6, pp = k & 63;
        const float bs = pbuf[0][gg][pp] + pbuf[1][gg][pp] +
                         pbuf[2][gg][pp] + pbuf[3][gg][pp];
        betaS[gg][pp] = bs;
        alphaS[gg][pp] = 1.f / (1.f + __expf(-bs));
    }
    __syncthreads();

    // iter 1: v1 = sum_g alpha1*con
    float a[8];
#pragma unroll
    for (int g = 0; g < 8; ++g) a[g] = alphaS[g][p];
#pragma unroll
    for (int f = 0; f < 16; ++f) {
        float s = 0.f;
#pragma unroll
        for (int g = 0; g < 8; ++g) s = fmaf(a[g], con[g][f], s);
        v[f] = s;
    }
    // beta2 = beta1 + sum_fo v1*con (partials; pbuf safe to rewrite: all prior
    // reads of pbuf happened before the last barrier)
#pragma unroll
    for (int g = 0; g < 8; ++g) {
        float s = 0.f;
#pragma unroll
        for (int f = 0; f < 16; ++f) s = fmaf(v[f], con[g][f], s);
        pbuf[q][g][p] = s;
    }
    __syncthreads();
    for (int k = tid; k < 512; k += 256) {
        const int gg = k >> 6, pp = k & 63;
        const float bs = betaS[gg][pp] +
                         pbuf[0][gg][pp] + pbuf[1][gg][pp] +
                         pbuf[2][gg][pp] + pbuf[3][gg][pp];
        alphaS[gg][pp] = 1.f / (1.f + __expf(-bs));
    }
    __syncthreads();

    // iter 2: out = sum_g alpha2*con + bias
#pragma unroll
    for (int g = 0; g < 8; ++g) a[g] = alphaS[g][p];

    const float* bq = bias + q * 16;
    float* orow = out + (((size_t)b * NFO + q * 16) * NH + h) * NW + p;
#pragma unroll
    for (int f = 0; f < 16; ++f) {
        float s = bq[f];
#pragma unroll
        for (int g = 0; g < 8; ++g) s = fmaf(a[g], con[g][f], s);
        orow[(size_t)f * HW] = s;
    }
}

extern "C" void kernel_launch(void* const* d_in, const int* in_sizes, int n_in,
                              void* d_out, int out_size, void* d_ws, size_t ws_size,
                              hipStream_t stream) {
    const float* x      = (const float*)d_in[0];
    const float* weight = (const float*)d_in[1];
    const float* bias   = (const float*)d_in[2];
    float* out = (float*)d_out;

    dynrout_kernel<<<dim3(NB * NH), dim3(256), 0, stream>>>(x, weight, bias, out);
}